// Round 1
// baseline (36.113 us; speedup 1.0000x reference)
//
#include <hip/hip_runtime.h>
#include <hip/hip_bf16.h>

#define NUM_CAMS 6
#define NQ       40000
#define MAX_LEN  10000
#define ED       256
#define NBLK     ((NQ + 255) / 256)   // 157

// d_out layout (float offsets)
#define OFF_IDX  0                                   // 6*10000
#define OFF_LEN  (NUM_CAMS * MAX_LEN)                // 60000, size 6
#define OFF_Q    (OFF_LEN + NUM_CAMS)                // 60006, size 15,360,000
#define OFF_REF  (OFF_Q + NUM_CAMS * MAX_LEN * ED)   // 15,420,006, size 480,000
#define OFF_CNT  (OFF_REF + NUM_CAMS * MAX_LEN * 8)  // 15,900,006, size 40,000

// ws layout (ints): [0, 6*NBLK) partials->offsets ; [6*NBLK, +6) totals ; [6*NBLK+6, +6) lens
#define WS_TOT   (NUM_CAMS * NBLK)
#define WS_LEN   (WS_TOT + NUM_CAMS)

__global__ void kA_counts(const int* __restrict__ bev, float* __restrict__ out,
                          int* __restrict__ ws) {
    __shared__ int cnt[NUM_CAMS];
    const int tid = threadIdx.x;
    const int blk = blockIdx.x;
    const int q   = blk * 256 + tid;
    if (tid < NUM_CAMS) cnt[tid] = 0;
    __syncthreads();
    const int lane = tid & 63;
    const bool inb = q < NQ;
    int myCount = 0;
    for (int cam = 0; cam < NUM_CAMS; ++cam) {
        bool v = false;
        if (inb) {
            const int4 m = *reinterpret_cast<const int4*>(bev + ((size_t)cam * NQ + q) * 4);
            v = (m.x > 0) || (m.y > 0) || (m.z > 0) || (m.w > 0);
        }
        myCount += v ? 1 : 0;
        unsigned long long bal = __ballot(v);
        if (lane == 0) atomicAdd(&cnt[cam], __popcll(bal));
    }
    if (inb) out[OFF_CNT + q] = 1.0f / fmaxf((float)myCount, 1.0f);
    __syncthreads();
    if (tid < NUM_CAMS) ws[tid * NBLK + blk] = cnt[tid];
}

__global__ void kB_scan(float* __restrict__ out, int* __restrict__ ws) {
    const int cam  = blockIdx.x;
    const int lane = threadIdx.x;  // 64 threads
    int running = 0;
    for (int base = 0; base < NBLK; base += 64) {
        const int i = base + lane;
        int val = (i < NBLK) ? ws[cam * NBLK + i] : 0;
        int v = val;
        for (int d = 1; d < 64; d <<= 1) {
            int n = __shfl_up(v, d, 64);
            if (lane >= d) v += n;
        }
        if (i < NBLK) ws[cam * NBLK + i] = v - val + running;  // exclusive
        running += __shfl(v, 63, 64);
    }
    if (lane == 0) {
        ws[WS_TOT + cam] = running;
        const int len = running < MAX_LEN ? running : MAX_LEN;
        ws[WS_LEN + cam] = len;
        out[OFF_LEN + cam] = (float)len;
    }
}

__global__ void kC_indexes(const int* __restrict__ bev, float* __restrict__ out,
                           const int* __restrict__ ws) {
    const int blk = blockIdx.x;
    const int cam = blockIdx.y;
    const int tid = threadIdx.x;
    const int q    = blk * 256 + tid;
    const int lane = tid & 63;
    const int wave = tid >> 6;
    const bool inb = q < NQ;
    bool v = false;
    if (inb) {
        const int4 m = *reinterpret_cast<const int4*>(bev + ((size_t)cam * NQ + q) * 4);
        v = (m.x > 0) || (m.y > 0) || (m.z > 0) || (m.w > 0);
    }
    const unsigned long long bal = __ballot(v);
    __shared__ int waveSums[4];
    if (lane == 0) waveSums[wave] = __popcll(bal);
    __syncthreads();
    int waveOff = 0;
    for (int w = 0; w < 4; ++w)
        if (w < wave) waveOff += waveSums[w];
    const int prefix   = __popcll(bal & ((1ull << lane) - 1ull));
    const int blockOff = ws[cam * NBLK + blk];
    const int total    = ws[WS_TOT + cam];
    if (inb) {
        const int vb  = blockOff + waveOff + prefix;      // valid strictly before q
        const int pos = v ? vb : (total + (q - vb));      // stable partition position
        if (pos < MAX_LEN) out[OFF_IDX + cam * MAX_LEN + pos] = (float)q;
    }
}

// 4 rows per 256-thread block, 64 lanes per row. float2 stores (out regions are
// only 8B-aligned: OFF_Q*4 % 16 == 8).
__global__ void kD_gather(const float* __restrict__ query, const float* __restrict__ refp,
                          float* __restrict__ out, const int* __restrict__ ws) {
    const int tid   = threadIdx.x;
    const int rowId = blockIdx.x * 4 + (tid >> 6);
    const int lane  = tid & 63;
    const int cam   = rowId / MAX_LEN;
    const int j     = rowId - cam * MAX_LEN;
    const int len   = ws[WS_LEN + cam];
    float* oq  = out + OFF_Q + (size_t)rowId * ED;
    float* orf = out + OFF_REF + (size_t)rowId * 8;
    if (j < len) {
        const int idx = (int)out[OFF_IDX + cam * MAX_LEN + j];
        const float4 v = *reinterpret_cast<const float4*>(query + (size_t)idx * ED + lane * 4);
        float2* o2 = reinterpret_cast<float2*>(oq + lane * 4);
        o2[0] = make_float2(v.x, v.y);
        o2[1] = make_float2(v.z, v.w);
        if (lane < 2) {
            const float4 r = *reinterpret_cast<const float4*>(refp + ((size_t)cam * NQ + idx) * 8 + lane * 4);
            float2* r2 = reinterpret_cast<float2*>(orf + lane * 4);
            r2[0] = make_float2(r.x, r.y);
            r2[1] = make_float2(r.z, r.w);
        }
    } else {
        float2* o2 = reinterpret_cast<float2*>(oq + lane * 4);
        o2[0] = make_float2(0.f, 0.f);
        o2[1] = make_float2(0.f, 0.f);
        if (lane < 2) {
            float2* r2 = reinterpret_cast<float2*>(orf + lane * 4);
            r2[0] = make_float2(0.f, 0.f);
            r2[1] = make_float2(0.f, 0.f);
        }
    }
}

extern "C" void kernel_launch(void* const* d_in, const int* in_sizes, int n_in,
                              void* d_out, int out_size, void* d_ws, size_t ws_size,
                              hipStream_t stream) {
    const float* query = (const float*)d_in[0];
    const float* refp  = (const float*)d_in[1];
    const int*   bev   = (const int*)d_in[2];
    float* out = (float*)d_out;
    int*   ws  = (int*)d_ws;

    kA_counts<<<NBLK, 256, 0, stream>>>(bev, out, ws);
    kB_scan<<<NUM_CAMS, 64, 0, stream>>>(out, ws);
    kC_indexes<<<dim3(NBLK, NUM_CAMS), 256, 0, stream>>>(bev, out, ws);
    kD_gather<<<(NUM_CAMS * MAX_LEN) / 4, 256, 0, stream>>>(query, refp, out, ws);
}